// Round 8
// baseline (146.014 us; speedup 1.0000x reference)
//
#include <hip/hip_runtime.h>

typedef __bf16 bf16x8 __attribute__((ext_vector_type(8)));
typedef __bf16 bf16x4 __attribute__((ext_vector_type(4)));
typedef __bf16 bf16x2 __attribute__((ext_vector_type(2)));
typedef float f32x4 __attribute__((ext_vector_type(4)));

#define NB 4
#define NC 64
#define NN 4096
#define SPLIT 8   // key-dim splits for flash

// sc folded into Q at qkv time: softmax uses exp2(q.k * 0.125 * log2(e))
#define QSCALE (0.125f * 1.44269504088896340736f)

#if __has_builtin(__builtin_amdgcn_exp2f)
#define EXP2(x) __builtin_amdgcn_exp2f(x)   // raw v_exp_f32; inputs are O(1)
#else
#define EXP2(x) exp2f(x)
#endif

// ---------------------------------------------------------------------------
// Kernel 1: QKV projection.  x:[B,C,N] fp32, w_qkv:[3C,C], b_qkv:[3C]
// Outputs: Q (pre-scaled), K as bf16 [B,N,C]; V as bf16 [B,C,N]
// grid(8, B, 24): z -> {q,k,v} x 8-output group.  768 blocks (3/CU).
// 2 n-positions/thread: each broadcast w-read feeds 8 FMAs.
// ---------------------------------------------------------------------------
__global__ __launch_bounds__(256) void qkv_kernel(
    const float* __restrict__ x, const float* __restrict__ wqkv,
    const float* __restrict__ bqkv,
    __bf16* __restrict__ Qg, __bf16* __restrict__ Kg, __bf16* __restrict__ Vg)
{
  const int tid = threadIdx.x;
  const int b = blockIdx.y;
  const int z = blockIdx.z;
  const int tsel = z >> 3;           // 0=q, 1=k, 2=v
  const int obase = (z & 7) * 8;     // which 8 output channels
  const int n = blockIdx.x * 512 + tid * 2;   // this thread: n, n+1
  const float wscale = (tsel == 0) ? QSCALE : 1.0f;

  __shared__ float wsh[8 * 64];      // 512 floats: 2 per thread
  __shared__ float bsh[8];
  wsh[tid]       = wqkv[(tsel * 64 + obase) * 64 + tid] * wscale;
  wsh[tid + 256] = wqkv[(tsel * 64 + obase) * 64 + tid + 256] * wscale;
  if (tid < 8) bsh[tid] = bqkv[tsel * 64 + obase + tid] * wscale;
  __syncthreads();

  float xa[64], xb[64];
#pragma unroll
  for (int c = 0; c < 64; c++) {
    const float2 t = *(const float2*)&x[((size_t)(b * 64 + c)) * NN + n];
    xa[c] = t.x; xb[c] = t.y;        // 8B/lane coalesced
  }

  float aa[8], ab[8];
#pragma unroll
  for (int j = 0; j < 8; j++) { aa[j] = bsh[j]; ab[j] = bsh[j]; }
#pragma unroll
  for (int c4 = 0; c4 < 64; c4 += 4) {
#pragma unroll
    for (int j = 0; j < 8; j++) {
      const float4 wv = *(const float4*)&wsh[j * 64 + c4];  // broadcast read
      aa[j] = fmaf(wv.x, xa[c4 + 0], aa[j]);
      aa[j] = fmaf(wv.y, xa[c4 + 1], aa[j]);
      aa[j] = fmaf(wv.z, xa[c4 + 2], aa[j]);
      aa[j] = fmaf(wv.w, xa[c4 + 3], aa[j]);
      ab[j] = fmaf(wv.x, xb[c4 + 0], ab[j]);
      ab[j] = fmaf(wv.y, xb[c4 + 1], ab[j]);
      ab[j] = fmaf(wv.z, xb[c4 + 2], ab[j]);
      ab[j] = fmaf(wv.w, xb[c4 + 3], ab[j]);
    }
  }

  if (tsel == 2) {
#pragma unroll
    for (int j = 0; j < 8; j++) {
      bf16x2 pv;
      pv[0] = (__bf16)aa[j]; pv[1] = (__bf16)ab[j];
      *(bf16x2*)(Vg + ((size_t)(b * 64 + obase + j)) * NN + n) = pv;
    }
  } else {
    __bf16* base = (tsel == 0 ? Qg : Kg);
    bf16x8 p0, p1;
#pragma unroll
    for (int j = 0; j < 8; j++) { p0[j] = (__bf16)aa[j]; p1[j] = (__bf16)ab[j]; }
    *(bf16x8*)(base + ((size_t)(b * NN + n)) * 64 + obase) = p0;
    *(bf16x8*)(base + ((size_t)(b * NN + n + 1)) * 64 + obase) = p1;
  }
}

// ---------------------------------------------------------------------------
// Kernel 2: flash attention, split-K, max-free softmax, BARRIER-FREE.
// K/V fragments load directly from global (b128, L1/L2-served; K-frag reads
// are fully coalesced 2KB/wave-pair).  LDS holds only per-wave ping-pong P^T
// scratch -> no __syncthreads anywhere; waves run fully asynchronously.
// S^T = mfma(kf, qf): lane's 4 P-values contiguous along key -> one bf16x4
// store; l is 1 accumulator/q-tile.  PV: O^T = mfma(vf, pf).
// Opart:[S,B,C,N] bf16 (unnorm), lpart:[S,B,N] float.
// grid(32, B, SPLIT), 256 thr = 4 waves; wave owns 32 q, block 128 q.
// ---------------------------------------------------------------------------
__global__ __launch_bounds__(256) void flash_kernel(
    const __bf16* __restrict__ Q, const __bf16* __restrict__ K,
    const __bf16* __restrict__ V, __bf16* __restrict__ Opart,
    float* __restrict__ lpart)
{
  const int b = blockIdx.y;
  const int s = blockIdx.z;
  const int tid = threadIdx.x;
  const int wave = tid >> 6;
  const int lane = tid & 63;
  const int quad = lane >> 4;
  const int l16 = lane & 15;

  __shared__ __bf16 Pt[4][2][32 * 72];   // per-wave ping-pong P^T [q(32)][key]

  const int q0 = blockIdx.x * 128 + wave * 32;

  // Q fragments (registers, loaded once)
  bf16x8 qf[2][2];
#pragma unroll
  for (int qt = 0; qt < 2; qt++) {
    const __bf16* qrow = Q + ((size_t)(b * NN + q0 + qt * 16 + l16)) * 64;
    qf[qt][0] = *(const bf16x8*)(qrow + quad * 8);
    qf[qt][1] = *(const bf16x8*)(qrow + 32 + quad * 8);
  }

  f32x4 acc[2][4];    // O^T acc: row c = ct*16+quad*4+r, col q = qt*16+l16
#pragma unroll
  for (int qt = 0; qt < 2; qt++)
#pragma unroll
    for (int ct = 0; ct < 4; ct++) acc[qt][ct] = (f32x4){0.f, 0.f, 0.f, 0.f};
  float l[2] = {0.f, 0.f};

  const int kbeg = s * (NN / SPLIT);
  const int ntiles = (NN / SPLIT) / 64;
#pragma unroll 1
  for (int it = 0; it < ntiles; it++) {
    const int kt0 = kbeg + it * 64;
    __bf16* P = Pt[wave][it & 1];

    // S^T = K Q^T ; K-frags straight from global (coalesced, L1/L2-hot)
#pragma unroll
    for (int t = 0; t < 4; t++) {
      const __bf16* krow = K + ((size_t)(b * NN + kt0 + t * 16 + l16)) * 64 + quad * 8;
      const bf16x8 kf0 = *(const bf16x8*)(krow);
      const bf16x8 kf1 = *(const bf16x8*)(krow + 32);
#pragma unroll
      for (int qt = 0; qt < 2; qt++) {
        f32x4 z = (f32x4){0.f, 0.f, 0.f, 0.f};
        z = __builtin_amdgcn_mfma_f32_16x16x32_bf16(kf0, qf[qt][0], z, 0, 0, 0);
        z = __builtin_amdgcn_mfma_f32_16x16x32_bf16(kf1, qf[qt][1], z, 0, 0, 0);
        const float p0 = EXP2(z[0]), p1 = EXP2(z[1]);
        const float p2 = EXP2(z[2]), p3 = EXP2(z[3]);
        l[qt] += (p0 + p1) + (p2 + p3);
        bf16x4 pk;
        pk[0] = (__bf16)p0; pk[1] = (__bf16)p1;
        pk[2] = (__bf16)p2; pk[3] = (__bf16)p3;
        *(bf16x4*)(&P[(qt * 16 + l16) * 72 + t * 16 + quad * 4]) = pk;
      }
    }

    // O^T += V^T P^T ; V-frags straight from global
#pragma unroll
    for (int kb = 0; kb < 2; kb++) {
      const bf16x8 pf0 = *(const bf16x8*)(&P[l16 * 72 + kb * 32 + quad * 8]);
      const bf16x8 pf1 = *(const bf16x8*)(&P[(16 + l16) * 72 + kb * 32 + quad * 8]);
#pragma unroll
      for (int ct = 0; ct < 4; ct++) {
        const bf16x8 vf = *(const bf16x8*)(
            V + ((size_t)(b * 64 + ct * 16 + l16)) * NN + kt0 + kb * 32 + quad * 8);
        acc[0][ct] = __builtin_amdgcn_mfma_f32_16x16x32_bf16(vf, pf0, acc[0][ct], 0, 0, 0);
        acc[1][ct] = __builtin_amdgcn_mfma_f32_16x16x32_bf16(vf, pf1, acc[1][ct], 0, 0, 0);
      }
    }
  }

  // epilogue: 2 shuffles per q-tile for l; O^T stores (16 lanes along n)
#pragma unroll
  for (int qt = 0; qt < 2; qt++) {
    float lr = l[qt];
    lr += __shfl_xor(lr, 16);
    lr += __shfl_xor(lr, 32);
    if (quad == 0)
      lpart[((size_t)(s * NB + b)) * NN + q0 + qt * 16 + l16] = lr;
#pragma unroll
    for (int ct = 0; ct < 4; ct++)
#pragma unroll
      for (int r = 0; r < 4; r++)
        Opart[(((size_t)(s * NB + b)) * 64 + ct * 16 + quad * 4 + r) * NN +
              q0 + qt * 16 + l16] = (__bf16)acc[qt][ct][r];
  }
}

// ---------------------------------------------------------------------------
// Kernel 3: fused combine + output projection + bias + residual.
// Opart:[S,B,C,N] bf16 -> transpose-free combine stage.
// grid(128, B) = 512 blocks; block = 32-n tile x all 64 channels.
// ---------------------------------------------------------------------------
__global__ __launch_bounds__(256) void combine_proj_kernel(
    const __bf16* __restrict__ Opart, const float* __restrict__ lpart,
    const float* __restrict__ wproj, const float* __restrict__ bproj,
    const float* __restrict__ x, float* __restrict__ out)
{
  const int b = blockIdx.y;
  const int n0 = blockIdx.x * 32;
  const int tid = threadIdx.x;

  __shared__ float Ot[64 * 36];   // [cin][n-tile 32], stride 36
  __shared__ float wT[64 * 66];   // [cin][cout], stride 66
  __shared__ float lsh[32];
  __shared__ float bsh[64];

  if (tid < 32) {
    float lt = 0.f;
#pragma unroll
    for (int s = 0; s < SPLIT; s++)
      lt += lpart[((size_t)(s * NB + b)) * NN + n0 + tid];
    lsh[tid] = 1.0f / lt;
  }
  if (tid < 64) bsh[tid] = bproj[tid];
#pragma unroll
  for (int k = 0; k < 16; k++) {
    const int i = tid + k * 256;        // i = cout*64 + cin
    wT[(i & 63) * 66 + (i >> 6)] = wproj[i];
  }
  __syncthreads();

  // combine stage, transpose-free: thread -> (cin = tid>>2, 8 n's)
  {
    const int c = tid >> 2;
    const int n8 = (tid & 3) * 8;
    float o[8];
#pragma unroll
    for (int j = 0; j < 8; j++) o[j] = 0.f;
#pragma unroll
    for (int s = 0; s < SPLIT; s++) {
      const bf16x8 v = *(const bf16x8*)(
          Opart + (((size_t)(s * NB + b)) * 64 + c) * NN + n0 + n8);
#pragma unroll
      for (int j = 0; j < 8; j++) o[j] += (float)v[j];
    }
#pragma unroll
    for (int j = 0; j < 8; j++) Ot[c * 36 + n8 + j] = o[j] * lsh[n8 + j];
  }
  __syncthreads();

  // micro-GEMM: thread -> 2 couts x 4 n
  const int co = (tid >> 3) * 2;
  const int ng = (tid & 7) * 4;
  float a0[4], a1[4];
#pragma unroll
  for (int j = 0; j < 4; j++) { a0[j] = bsh[co]; a1[j] = bsh[co + 1]; }
  for (int cin = 0; cin < 64; cin++) {
    const float4 ov = *(const float4*)&Ot[cin * 36 + ng];
    const float2 wv = *(const float2*)&wT[cin * 66 + co];
    a0[0] = fmaf(wv.x, ov.x, a0[0]); a0[1] = fmaf(wv.x, ov.y, a0[1]);
    a0[2] = fmaf(wv.x, ov.z, a0[2]); a0[3] = fmaf(wv.x, ov.w, a0[3]);
    a1[0] = fmaf(wv.y, ov.x, a1[0]); a1[1] = fmaf(wv.y, ov.y, a1[1]);
    a1[2] = fmaf(wv.y, ov.z, a1[2]); a1[3] = fmaf(wv.y, ov.w, a1[3]);
  }

  // residual + write (8-lane groups cover 128B contiguous per cout row)
#pragma unroll
  for (int i = 0; i < 2; i++) {
    float* ai = (i == 0) ? a0 : a1;
    const size_t base = ((size_t)(b * 64 + co + i)) * NN + n0 + ng;
    const float4 xr = *(const float4*)&x[base];
    float4 r;
    r.x = ai[0] + xr.x; r.y = ai[1] + xr.y;
    r.z = ai[2] + xr.z; r.w = ai[3] + xr.w;
    *(float4*)&out[base] = r;
  }
}

extern "C" void kernel_launch(void* const* d_in, const int* in_sizes, int n_in,
                              void* d_out, int out_size, void* d_ws, size_t ws_size,
                              hipStream_t stream) {
  const float* x     = (const float*)d_in[0];
  const float* wqkv  = (const float*)d_in[1];
  const float* bqkv  = (const float*)d_in[2];
  const float* wproj = (const float*)d_in[3];
  const float* bproj = (const float*)d_in[4];
  float* out = (float*)d_out;

  // Workspace: Q[0,2M) K[2,4M) V[4,6M) Opart[6,22M) l[23M,23.5M)
  char* ws = (char*)d_ws;
  __bf16* Q     = (__bf16*)(ws);
  __bf16* K     = (__bf16*)(ws + (2u << 20));
  __bf16* V     = (__bf16*)(ws + (4u << 20));
  __bf16* Opart = (__bf16*)(ws + (6u << 20));   // [S,B,C,N] = 16 MiB
  float*  lpart = (float*)(ws + (23u << 20));   // SPLIT*B*N*4 = 512 KiB

  qkv_kernel<<<dim3(8, NB, 24), 256, 0, stream>>>(x, wqkv, bqkv, Q, K, V);
  flash_kernel<<<dim3(32, NB, SPLIT), 256, 0, stream>>>(Q, K, V, Opart, lpart);
  combine_proj_kernel<<<dim3(128, NB), 256, 0, stream>>>(Opart, lpart, wproj,
                                                         bproj, x, out);
}

// Round 9
// 137.101 us; speedup vs baseline: 1.0650x; 1.0650x over previous
//
#include <hip/hip_runtime.h>

typedef __bf16 bf16x8 __attribute__((ext_vector_type(8)));
typedef __bf16 bf16x4 __attribute__((ext_vector_type(4)));
typedef __bf16 bf16x2 __attribute__((ext_vector_type(2)));
typedef float f32x4 __attribute__((ext_vector_type(4)));

#define NB 4
#define NC 64
#define NN 4096
#define SPLIT 8   // key-dim splits for flash

// sc folded into Q at qkv time: softmax uses exp2(q.k * 0.125 * log2(e))
#define QSCALE (0.125f * 1.44269504088896340736f)

#if __has_builtin(__builtin_amdgcn_exp2f)
#define EXP2(x) __builtin_amdgcn_exp2f(x)   // raw v_exp_f32; inputs are O(1)
#else
#define EXP2(x) exp2f(x)
#endif

// async global->LDS DMA, 16B per lane; LDS dest = wave-uniform base + lane*16
typedef __attribute__((address_space(3))) unsigned int lds_u32;
typedef __attribute__((address_space(1))) unsigned int glob_u32;
__device__ __forceinline__ void ld_g2l_16(void* lds_base, const void* g) {
  __builtin_amdgcn_global_load_lds((const glob_u32*)g, (lds_u32*)lds_base,
                                   16, 0, 0);
}

// ---------------------------------------------------------------------------
// Kernel 1: QKV projection.  x:[B,C,N] fp32, w_qkv:[3C,C], b_qkv:[3C]
// Outputs: Q (pre-scaled), K as bf16 [B,N,C]; V as bf16 [B,C,N]
// grid(8, B, 24): z -> {q,k,v} x 8-output group.  768 blocks (3/CU).
// ---------------------------------------------------------------------------
__global__ __launch_bounds__(256) void qkv_kernel(
    const float* __restrict__ x, const float* __restrict__ wqkv,
    const float* __restrict__ bqkv,
    __bf16* __restrict__ Qg, __bf16* __restrict__ Kg, __bf16* __restrict__ Vg)
{
  const int tid = threadIdx.x;
  const int b = blockIdx.y;
  const int z = blockIdx.z;
  const int tsel = z >> 3;           // 0=q, 1=k, 2=v
  const int obase = (z & 7) * 8;     // which 8 output channels
  const int n = blockIdx.x * 512 + tid * 2;   // this thread: n, n+1
  const float wscale = (tsel == 0) ? QSCALE : 1.0f;

  __shared__ float wsh[8 * 64];      // 512 floats: 2 per thread
  __shared__ float bsh[8];
  wsh[tid]       = wqkv[(tsel * 64 + obase) * 64 + tid] * wscale;
  wsh[tid + 256] = wqkv[(tsel * 64 + obase) * 64 + tid + 256] * wscale;
  if (tid < 8) bsh[tid] = bqkv[tsel * 64 + obase + tid] * wscale;
  __syncthreads();

  float xa[64], xb[64];
#pragma unroll
  for (int c = 0; c < 64; c++) {
    const float2 t = *(const float2*)&x[((size_t)(b * 64 + c)) * NN + n];
    xa[c] = t.x; xb[c] = t.y;        // 8B/lane coalesced
  }

  float aa[8], ab[8];
#pragma unroll
  for (int j = 0; j < 8; j++) { aa[j] = bsh[j]; ab[j] = bsh[j]; }
#pragma unroll
  for (int c4 = 0; c4 < 64; c4 += 4) {
#pragma unroll
    for (int j = 0; j < 8; j++) {
      const float4 wv = *(const float4*)&wsh[j * 64 + c4];  // broadcast read
      aa[j] = fmaf(wv.x, xa[c4 + 0], aa[j]);
      aa[j] = fmaf(wv.y, xa[c4 + 1], aa[j]);
      aa[j] = fmaf(wv.z, xa[c4 + 2], aa[j]);
      aa[j] = fmaf(wv.w, xa[c4 + 3], aa[j]);
      ab[j] = fmaf(wv.x, xb[c4 + 0], ab[j]);
      ab[j] = fmaf(wv.y, xb[c4 + 1], ab[j]);
      ab[j] = fmaf(wv.z, xb[c4 + 2], ab[j]);
      ab[j] = fmaf(wv.w, xb[c4 + 3], ab[j]);
    }
  }

  if (tsel == 2) {
#pragma unroll
    for (int j = 0; j < 8; j++) {
      bf16x2 pv;
      pv[0] = (__bf16)aa[j]; pv[1] = (__bf16)ab[j];
      *(bf16x2*)(Vg + ((size_t)(b * 64 + obase + j)) * NN + n) = pv;
    }
  } else {
    __bf16* base = (tsel == 0 ? Qg : Kg);
    bf16x8 p0, p1;
#pragma unroll
    for (int j = 0; j < 8; j++) { p0[j] = (__bf16)aa[j]; p1[j] = (__bf16)ab[j]; }
    *(bf16x8*)(base + ((size_t)(b * NN + n)) * 64 + obase) = p0;
    *(bf16x8*)(base + ((size_t)(b * NN + n + 1)) * 64 + obase) = p1;
  }
}

// ---------------------------------------------------------------------------
// Kernel 2: flash attention, split-K, max-free softmax, hybrid staging.
// K-fragments: straight from global (coalesced 16-line reads, L1-hot across
// the 4 waves).  V: async-DMA (global_load_lds w16) into double-buffered,
// UNPADDED, XOR-SWIZZLED LDS (chunk slot = c*8 + (ch ^ (c&7)) -> staging is
// line-coalesced AND vf reads are 2-way-free on banks).  ONE barrier/tile:
// barrier -> prefetch tile i+1 -> compute tile i.
// P^T per-wave single-buffer (padded 72).  Math identical to R7 (verified):
// S^T = mfma(kf,qf), P^T bf16x4 stores, O^T = mfma(vf,pf).
// Opart:[S,B,C,N] bf16 (unnorm), lpart:[S,B,N] float.
// grid(32, B, SPLIT), 256 thr = 4 waves; wave owns 32 q, block 128 q.
// ---------------------------------------------------------------------------
__global__ __launch_bounds__(256) void flash_kernel(
    const __bf16* __restrict__ Q, const __bf16* __restrict__ K,
    const __bf16* __restrict__ V, __bf16* __restrict__ Opart,
    float* __restrict__ lpart)
{
  const int b = blockIdx.y;
  const int s = blockIdx.z;
  const int tid = threadIdx.x;
  const int wave = tid >> 6;
  const int lane = tid & 63;
  const int quad = lane >> 4;
  const int l16 = lane & 15;

  __shared__ __bf16 Vt[2][64 * 64];    // swizzled, unpadded (DMA dest)
  __shared__ __bf16 Pt[4][32 * 72];    // per-wave P^T [q(32)][key], padded

  const int q0 = blockIdx.x * 128 + wave * 32;
  const int kbeg = s * (NN / SPLIT);
  const int ntiles = (NN / SPLIT) / 64;

  // Q fragments (registers, loaded once)
  bf16x8 qf[2][2];
#pragma unroll
  for (int qt = 0; qt < 2; qt++) {
    const __bf16* qrow = Q + ((size_t)(b * NN + q0 + qt * 16 + l16)) * 64;
    qf[qt][0] = *(const bf16x8*)(qrow + quad * 8);
    qf[qt][1] = *(const bf16x8*)(qrow + 32 + quad * 8);
  }

  f32x4 acc[2][4];    // O^T acc: row c = ct*16+quad*4+r, col q = qt*16+l16
#pragma unroll
  for (int qt = 0; qt < 2; qt++)
#pragma unroll
    for (int ct = 0; ct < 4; ct++) acc[qt][ct] = (f32x4){0.f, 0.f, 0.f, 0.f};
  float l[2] = {0.f, 0.f};

  // stage V tile `it` into Vt[buf]: 2 DMA calls/wave, slots wave*128+j*64+lane
  auto stage_v = [&](int it, int buf) {
#pragma unroll
    for (int j = 0; j < 2; j++) {
      const int sl = wave * 128 + j * 64 + lane;      // chunk slot 0..511
      const int c = sl >> 3;
      const int ch = (sl & 7) ^ (c & 7);              // XOR swizzle
      const __bf16* g = V + ((size_t)(b * 64 + c)) * NN +
                        (kbeg + it * 64) + ch * 8;
      ld_g2l_16(&Vt[buf][(wave * 128 + j * 64) * 8], g);
    }
  };

  stage_v(0, 0);

  const int xr = l16 & 7;              // lane-const part of read swizzle

#pragma unroll 1
  for (int it = 0; it < ntiles; it++) {
    __syncthreads();                   // drains DMA of tile it; frees other buf
    if (it + 1 < ntiles) stage_v(it + 1, (it + 1) & 1);

    const int kt0 = kbeg + it * 64;
    const __bf16* Vb = Vt[it & 1];
    __bf16* P = Pt[wave];

    // S^T = K Q^T ; K-frags straight from global (coalesced, L1-hot)
#pragma unroll
    for (int t = 0; t < 4; t++) {
      const __bf16* krow =
          K + ((size_t)(b * NN + kt0 + t * 16 + l16)) * 64 + quad * 8;
      const bf16x8 kf0 = *(const bf16x8*)(krow);
      const bf16x8 kf1 = *(const bf16x8*)(krow + 32);
#pragma unroll
      for (int qt = 0; qt < 2; qt++) {
        f32x4 z = (f32x4){0.f, 0.f, 0.f, 0.f};
        z = __builtin_amdgcn_mfma_f32_16x16x32_bf16(kf0, qf[qt][0], z, 0, 0, 0);
        z = __builtin_amdgcn_mfma_f32_16x16x32_bf16(kf1, qf[qt][1], z, 0, 0, 0);
        const float p0 = EXP2(z[0]), p1 = EXP2(z[1]);
        const float p2 = EXP2(z[2]), p3 = EXP2(z[3]);
        l[qt] += (p0 + p1) + (p2 + p3);
        bf16x4 pk;
        pk[0] = (__bf16)p0; pk[1] = (__bf16)p1;
        pk[2] = (__bf16)p2; pk[3] = (__bf16)p3;
        *(bf16x4*)(&P[(qt * 16 + l16) * 72 + t * 16 + quad * 4]) = pk;
      }
    }

    // O^T += V^T P^T ; vf from swizzled LDS
#pragma unroll
    for (int kb = 0; kb < 2; kb++) {
      const bf16x8 pf0 = *(const bf16x8*)(&P[l16 * 72 + kb * 32 + quad * 8]);
      const bf16x8 pf1 = *(const bf16x8*)(&P[(16 + l16) * 72 + kb * 32 + quad * 8]);
#pragma unroll
      for (int ct = 0; ct < 4; ct++) {
        const int row = ct * 16 + l16;
        const int x = (kb * 4 + quad) ^ xr;           // swizzled chunk
        const bf16x8 vf = *(const bf16x8*)(&Vb[row * 64 + x * 8]);
        acc[0][ct] = __builtin_amdgcn_mfma_f32_16x16x32_bf16(vf, pf0, acc[0][ct], 0, 0, 0);
        acc[1][ct] = __builtin_amdgcn_mfma_f32_16x16x32_bf16(vf, pf1, acc[1][ct], 0, 0, 0);
      }
    }
  }

  // epilogue: 2 shuffles per q-tile for l; O^T stores (16 lanes along n)
#pragma unroll
  for (int qt = 0; qt < 2; qt++) {
    float lr = l[qt];
    lr += __shfl_xor(lr, 16);
    lr += __shfl_xor(lr, 32);
    if (quad == 0)
      lpart[((size_t)(s * NB + b)) * NN + q0 + qt * 16 + l16] = lr;
#pragma unroll
    for (int ct = 0; ct < 4; ct++)
#pragma unroll
      for (int r = 0; r < 4; r++)
        Opart[(((size_t)(s * NB + b)) * 64 + ct * 16 + quad * 4 + r) * NN +
              q0 + qt * 16 + l16] = (__bf16)acc[qt][ct][r];
  }
}

// ---------------------------------------------------------------------------
// Kernel 3: fused combine + output projection + bias + residual.
// Opart:[S,B,C,N] bf16 -> transpose-free combine stage.
// grid(128, B) = 512 blocks; block = 32-n tile x all 64 channels.
// ---------------------------------------------------------------------------
__global__ __launch_bounds__(256) void combine_proj_kernel(
    const __bf16* __restrict__ Opart, const float* __restrict__ lpart,
    const float* __restrict__ wproj, const float* __restrict__ bproj,
    const float* __restrict__ x, float* __restrict__ out)
{
  const int b = blockIdx.y;
  const int n0 = blockIdx.x * 32;
  const int tid = threadIdx.x;

  __shared__ float Ot[64 * 36];   // [cin][n-tile 32], stride 36
  __shared__ float wT[64 * 66];   // [cin][cout], stride 66
  __shared__ float lsh[32];
  __shared__ float bsh[64];

  if (tid < 32) {
    float lt = 0.f;
#pragma unroll
    for (int s = 0; s < SPLIT; s++)
      lt += lpart[((size_t)(s * NB + b)) * NN + n0 + tid];
    lsh[tid] = 1.0f / lt;
  }
  if (tid < 64) bsh[tid] = bproj[tid];
#pragma unroll
  for (int k = 0; k < 16; k++) {
    const int i = tid + k * 256;        // i = cout*64 + cin
    wT[(i & 63) * 66 + (i >> 6)] = wproj[i];
  }
  __syncthreads();

  // combine stage, transpose-free: thread -> (cin = tid>>2, 8 n's)
  {
    const int c = tid >> 2;
    const int n8 = (tid & 3) * 8;
    float o[8];
#pragma unroll
    for (int j = 0; j < 8; j++) o[j] = 0.f;
#pragma unroll
    for (int s = 0; s < SPLIT; s++) {
      const bf16x8 v = *(const bf16x8*)(
          Opart + (((size_t)(s * NB + b)) * 64 + c) * NN + n0 + n8);
#pragma unroll
      for (int j = 0; j < 8; j++) o[j] += (float)v[j];
    }
#pragma unroll
    for (int j = 0; j < 8; j++) Ot[c * 36 + n8 + j] = o[j] * lsh[n8 + j];
  }
  __syncthreads();

  // micro-GEMM: thread -> 2 couts x 4 n
  const int co = (tid >> 3) * 2;
  const int ng = (tid & 7) * 4;
  float a0[4], a1[4];
#pragma unroll
  for (int j = 0; j < 4; j++) { a0[j] = bsh[co]; a1[j] = bsh[co + 1]; }
  for (int cin = 0; cin < 64; cin++) {
    const float4 ov = *(const float4*)&Ot[cin * 36 + ng];
    const float2 wv = *(const float2*)&wT[cin * 66 + co];
    a0[0] = fmaf(wv.x, ov.x, a0[0]); a0[1] = fmaf(wv.x, ov.y, a0[1]);
    a0[2] = fmaf(wv.x, ov.z, a0[2]); a0[3] = fmaf(wv.x, ov.w, a0[3]);
    a1[0] = fmaf(wv.y, ov.x, a1[0]); a1[1] = fmaf(wv.y, ov.y, a1[1]);
    a1[2] = fmaf(wv.y, ov.z, a1[2]); a1[3] = fmaf(wv.y, ov.w, a1[3]);
  }

  // residual + write (8-lane groups cover 128B contiguous per cout row)
#pragma unroll
  for (int i = 0; i < 2; i++) {
    float* ai = (i == 0) ? a0 : a1;
    const size_t base = ((size_t)(b * 64 + co + i)) * NN + n0 + ng;
    const float4 xr = *(const float4*)&x[base];
    float4 r;
    r.x = ai[0] + xr.x; r.y = ai[1] + xr.y;
    r.z = ai[2] + xr.z; r.w = ai[3] + xr.w;
    *(float4*)&out[base] = r;
  }
}

extern "C" void kernel_launch(void* const* d_in, const int* in_sizes, int n_in,
                              void* d_out, int out_size, void* d_ws, size_t ws_size,
                              hipStream_t stream) {
  const float* x     = (const float*)d_in[0];
  const float* wqkv  = (const float*)d_in[1];
  const float* bqkv  = (const float*)d_in[2];
  const float* wproj = (const float*)d_in[3];
  const float* bproj = (const float*)d_in[4];
  float* out = (float*)d_out;

  // Workspace: Q[0,2M) K[2,4M) V[4,6M) Opart[6,22M) l[23M,23.5M)
  char* ws = (char*)d_ws;
  __bf16* Q     = (__bf16*)(ws);
  __bf16* K     = (__bf16*)(ws + (2u << 20));
  __bf16* V     = (__bf16*)(ws + (4u << 20));
  __bf16* Opart = (__bf16*)(ws + (6u << 20));   // [S,B,C,N] = 16 MiB
  float*  lpart = (float*)(ws + (23u << 20));   // SPLIT*B*N*4 = 512 KiB

  qkv_kernel<<<dim3(8, NB, 24), 256, 0, stream>>>(x, wqkv, bqkv, Q, K, V);
  flash_kernel<<<dim3(32, NB, SPLIT), 256, 0, stream>>>(Q, K, V, Opart, lpart);
  combine_proj_kernel<<<dim3(128, NB), 256, 0, stream>>>(Opart, lpart, wproj,
                                                         bproj, x, out);
}

// Round 10
// 113.712 us; speedup vs baseline: 1.2841x; 1.2057x over previous
//
#include <hip/hip_runtime.h>

typedef __bf16 bf16x8 __attribute__((ext_vector_type(8)));
typedef __bf16 bf16x4 __attribute__((ext_vector_type(4)));
typedef __bf16 bf16x2 __attribute__((ext_vector_type(2)));
typedef float f32x4 __attribute__((ext_vector_type(4)));
typedef short s16x4 __attribute__((ext_vector_type(4)));

#define NB 4
#define NC 64
#define NN 4096
#define SPLIT 8   // key-dim splits for flash

// sc folded into Q at qkv time: softmax uses exp2(q.k * 0.125 * log2(e))
#define QSCALE (0.125f * 1.44269504088896340736f)

#if __has_builtin(__builtin_amdgcn_exp2f)
#define EXP2(x) __builtin_amdgcn_exp2f(x)   // raw v_exp_f32; inputs are O(1)
#else
#define EXP2(x) exp2f(x)
#endif

// ---------------------------------------------------------------------------
// Kernel 1: QKV projection (R7-exact, known good).
// x:[B,C,N] fp32 -> Q (pre-scaled), K bf16 [B,N,C]; V bf16 [B,C,N]
// grid(8, B, 24): z -> {q,k,v} x 8-output group.  768 blocks.
// ---------------------------------------------------------------------------
__global__ __launch_bounds__(256) void qkv_kernel(
    const float* __restrict__ x, const float* __restrict__ wqkv,
    const float* __restrict__ bqkv,
    __bf16* __restrict__ Qg, __bf16* __restrict__ Kg, __bf16* __restrict__ Vg)
{
  const int tid = threadIdx.x;
  const int b = blockIdx.y;
  const int z = blockIdx.z;
  const int tsel = z >> 3;           // 0=q, 1=k, 2=v
  const int obase = (z & 7) * 8;     // which 8 output channels
  const int n = blockIdx.x * 512 + tid * 2;   // this thread: n, n+1
  const float wscale = (tsel == 0) ? QSCALE : 1.0f;

  __shared__ float wsh[8 * 64];      // 512 floats: 2 per thread
  __shared__ float bsh[8];
  wsh[tid]       = wqkv[(tsel * 64 + obase) * 64 + tid] * wscale;
  wsh[tid + 256] = wqkv[(tsel * 64 + obase) * 64 + tid + 256] * wscale;
  if (tid < 8) bsh[tid] = bqkv[tsel * 64 + obase + tid] * wscale;
  __syncthreads();

  float xa[64], xb[64];
#pragma unroll
  for (int c = 0; c < 64; c++) {
    const float2 t = *(const float2*)&x[((size_t)(b * 64 + c)) * NN + n];
    xa[c] = t.x; xb[c] = t.y;        // 8B/lane coalesced
  }

  float aa[8], ab[8];
#pragma unroll
  for (int j = 0; j < 8; j++) { aa[j] = bsh[j]; ab[j] = bsh[j]; }
#pragma unroll
  for (int c4 = 0; c4 < 64; c4 += 4) {
#pragma unroll
    for (int j = 0; j < 8; j++) {
      const float4 wv = *(const float4*)&wsh[j * 64 + c4];  // broadcast read
      aa[j] = fmaf(wv.x, xa[c4 + 0], aa[j]);
      aa[j] = fmaf(wv.y, xa[c4 + 1], aa[j]);
      aa[j] = fmaf(wv.z, xa[c4 + 2], aa[j]);
      aa[j] = fmaf(wv.w, xa[c4 + 3], aa[j]);
      ab[j] = fmaf(wv.x, xb[c4 + 0], ab[j]);
      ab[j] = fmaf(wv.y, xb[c4 + 1], ab[j]);
      ab[j] = fmaf(wv.z, xb[c4 + 2], ab[j]);
      ab[j] = fmaf(wv.w, xb[c4 + 3], ab[j]);
    }
  }

  if (tsel == 2) {
#pragma unroll
    for (int j = 0; j < 8; j++) {
      bf16x2 pv;
      pv[0] = (__bf16)aa[j]; pv[1] = (__bf16)ab[j];
      *(bf16x2*)(Vg + ((size_t)(b * 64 + obase + j)) * NN + n) = pv;
    }
  } else {
    __bf16* base = (tsel == 0 ? Qg : Kg);
    bf16x8 p0, p1;
#pragma unroll
    for (int j = 0; j < 8; j++) { p0[j] = (__bf16)aa[j]; p1[j] = (__bf16)ab[j]; }
    *(bf16x8*)(base + ((size_t)(b * NN + n)) * 64 + obase) = p0;
    *(bf16x8*)(base + ((size_t)(b * NN + n + 1)) * 64 + obase) = p1;
  }
}

// ---------------------------------------------------------------------------
// Kernel 2: flash attention, split-K, max-free softmax.
// R7 2-barrier staged shell (verified fastest) + P-IN-REGISTER dataflow:
// S^T = mfma_16x16x32(kf, qf) -> exp2 -> bf16x4 pk held in VGPRs.  The S^T
// C/D layout (row=key=quad*4+r, col=q=l16) IS the B-operand layout of
// v_mfma_f32_16x16x16_bf16 (B[k=quad*4+j][n=lane&15]), so PV chains 4 K=16
// MFMAs per 64-key tile with A = V^T b64 frags (A[m=c=l16][k=quad*4+j]).
// -> zero P LDS traffic, no Pt buffer (LDS 18.4KB/block), no intra-tile
// lgkmcnt serialization.  Opart:[S,B,C,N] bf16 (unnorm), lpart:[S,B,N].
// grid(32, B, SPLIT), 256 thr = 4 waves; wave owns 32 q, block 128 q.
// ---------------------------------------------------------------------------
__global__ __launch_bounds__(256) void flash_kernel(
    const __bf16* __restrict__ Q, const __bf16* __restrict__ K,
    const __bf16* __restrict__ V, __bf16* __restrict__ Opart,
    float* __restrict__ lpart)
{
  const int b = blockIdx.y;
  const int s = blockIdx.z;
  const int tid = threadIdx.x;
  const int wave = tid >> 6;
  const int lane = tid & 63;
  const int quad = lane >> 4;
  const int l16 = lane & 15;

  __shared__ __bf16 Kt[64 * 72];      // [key][c], padded
  __shared__ __bf16 Vt[64 * 72];      // [c][key], padded

  const int q0 = blockIdx.x * 128 + wave * 32;

  // Q fragments (registers, loaded once)
  bf16x8 qf[2][2];
#pragma unroll
  for (int qt = 0; qt < 2; qt++) {
    const __bf16* qrow = Q + ((size_t)(b * NN + q0 + qt * 16 + l16)) * 64;
    qf[qt][0] = *(const bf16x8*)(qrow + quad * 8);
    qf[qt][1] = *(const bf16x8*)(qrow + 32 + quad * 8);
  }

  f32x4 acc[2][4];    // O^T acc: row c = ct*16+quad*4+r, col q = qt*16+l16
#pragma unroll
  for (int qt = 0; qt < 2; qt++)
#pragma unroll
    for (int ct = 0; ct < 4; ct++) acc[qt][ct] = (f32x4){0.f, 0.f, 0.f, 0.f};
  float l[2] = {0.f, 0.f};

  const int kbeg = s * (NN / SPLIT);
  const int kend = kbeg + (NN / SPLIT);
#pragma unroll 1
  for (int kt0 = kbeg; kt0 < kend; kt0 += 64) {
    __syncthreads();
#pragma unroll
    for (int it = 0; it < 2; it++) {
      const int chunk = tid + it * 256;          // 512 chunks of 8 bf16
      const int row = chunk >> 3, col8 = (chunk & 7) * 8;
      *(bf16x8*)(&Kt[row * 72 + col8]) =
          *(const bf16x8*)(K + ((size_t)(b * NN + kt0 + row)) * 64 + col8);
      *(bf16x8*)(&Vt[row * 72 + col8]) =
          *(const bf16x8*)(V + ((size_t)(b * 64 + row)) * NN + kt0 + col8);
    }
    __syncthreads();

    // ---- S^T = K Q^T, P packed into registers --------------------------
    s16x4 pk[4][2];
#pragma unroll
    for (int t = 0; t < 4; t++) {
      const bf16x8 kf0 = *(const bf16x8*)(&Kt[(t * 16 + l16) * 72 + quad * 8]);
      const bf16x8 kf1 = *(const bf16x8*)(&Kt[(t * 16 + l16) * 72 + 32 + quad * 8]);
#pragma unroll
      for (int qt = 0; qt < 2; qt++) {
        f32x4 z = (f32x4){0.f, 0.f, 0.f, 0.f};
        z = __builtin_amdgcn_mfma_f32_16x16x32_bf16(kf0, qf[qt][0], z, 0, 0, 0);
        z = __builtin_amdgcn_mfma_f32_16x16x32_bf16(kf1, qf[qt][1], z, 0, 0, 0);
        const float p0 = EXP2(z[0]), p1 = EXP2(z[1]);
        const float p2 = EXP2(z[2]), p3 = EXP2(z[3]);
        l[qt] += (p0 + p1) + (p2 + p3);
        bf16x4 pv;
        pv[0] = (__bf16)p0; pv[1] = (__bf16)p1;
        pv[2] = (__bf16)p2; pv[3] = (__bf16)p3;
        pk[t][qt] = __builtin_bit_cast(s16x4, pv);
      }
    }

    // ---- O^T += V^T P^T : K=16 MFMAs, P straight from registers --------
#pragma unroll
    for (int kg = 0; kg < 4; kg++) {
#pragma unroll
      for (int ct = 0; ct < 4; ct++) {
        const bf16x4 va =
            *(const bf16x4*)(&Vt[(ct * 16 + l16) * 72 + kg * 16 + quad * 4]);
        const s16x4 a = __builtin_bit_cast(s16x4, va);
        acc[0][ct] = __builtin_amdgcn_mfma_f32_16x16x16bf16_1k(
            a, pk[kg][0], acc[0][ct], 0, 0, 0);
        acc[1][ct] = __builtin_amdgcn_mfma_f32_16x16x16bf16_1k(
            a, pk[kg][1], acc[1][ct], 0, 0, 0);
      }
    }
  }

  // epilogue: 2 shuffles per q-tile for l; O^T stores (16 lanes along n)
#pragma unroll
  for (int qt = 0; qt < 2; qt++) {
    float lr = l[qt];
    lr += __shfl_xor(lr, 16);
    lr += __shfl_xor(lr, 32);
    if (quad == 0)
      lpart[((size_t)(s * NB + b)) * NN + q0 + qt * 16 + l16] = lr;
#pragma unroll
    for (int ct = 0; ct < 4; ct++)
#pragma unroll
      for (int r = 0; r < 4; r++)
        Opart[(((size_t)(s * NB + b)) * 64 + ct * 16 + quad * 4 + r) * NN +
              q0 + qt * 16 + l16] = (__bf16)acc[qt][ct][r];
  }
}

// ---------------------------------------------------------------------------
// Kernel 3: fused combine + output projection + bias + residual (R7-exact).
// Opart:[S,B,C,N] bf16 -> transpose-free combine stage.
// grid(128, B) = 512 blocks; block = 32-n tile x all 64 channels.
// ---------------------------------------------------------------------------
__global__ __launch_bounds__(256) void combine_proj_kernel(
    const __bf16* __restrict__ Opart, const float* __restrict__ lpart,
    const float* __restrict__ wproj, const float* __restrict__ bproj,
    const float* __restrict__ x, float* __restrict__ out)
{
  const int b = blockIdx.y;
  const int n0 = blockIdx.x * 32;
  const int tid = threadIdx.x;

  __shared__ float Ot[64 * 36];   // [cin][n-tile 32], stride 36
  __shared__ float wT[64 * 66];   // [cin][cout], stride 66
  __shared__ float lsh[32];
  __shared__ float bsh[64];

  if (tid < 32) {
    float lt = 0.f;
#pragma unroll
    for (int s = 0; s < SPLIT; s++)
      lt += lpart[((size_t)(s * NB + b)) * NN + n0 + tid];
    lsh[tid] = 1.0f / lt;
  }
  if (tid < 64) bsh[tid] = bproj[tid];
#pragma unroll
  for (int k = 0; k < 16; k++) {
    const int i = tid + k * 256;        // i = cout*64 + cin
    wT[(i & 63) * 66 + (i >> 6)] = wproj[i];
  }
  __syncthreads();

  // combine stage, transpose-free: thread -> (cin = tid>>2, 8 n's)
  {
    const int c = tid >> 2;
    const int n8 = (tid & 3) * 8;
    float o[8];
#pragma unroll
    for (int j = 0; j < 8; j++) o[j] = 0.f;
#pragma unroll
    for (int s = 0; s < SPLIT; s++) {
      const bf16x8 v = *(const bf16x8*)(
          Opart + (((size_t)(s * NB + b)) * 64 + c) * NN + n0 + n8);
#pragma unroll
      for (int j = 0; j < 8; j++) o[j] += (float)v[j];
    }
#pragma unroll
    for (int j = 0; j < 8; j++) Ot[c * 36 + n8 + j] = o[j] * lsh[n8 + j];
  }
  __syncthreads();

  // micro-GEMM: thread -> 2 couts x 4 n
  const int co = (tid >> 3) * 2;
  const int ng = (tid & 7) * 4;
  float a0[4], a1[4];
#pragma unroll
  for (int j = 0; j < 4; j++) { a0[j] = bsh[co]; a1[j] = bsh[co + 1]; }
  for (int cin = 0; cin < 64; cin++) {
    const float4 ov = *(const float4*)&Ot[cin * 36 + ng];
    const float2 wv = *(const float2*)&wT[cin * 66 + co];
    a0[0] = fmaf(wv.x, ov.x, a0[0]); a0[1] = fmaf(wv.x, ov.y, a0[1]);
    a0[2] = fmaf(wv.x, ov.z, a0[2]); a0[3] = fmaf(wv.x, ov.w, a0[3]);
    a1[0] = fmaf(wv.y, ov.x, a1[0]); a1[1] = fmaf(wv.y, ov.y, a1[1]);
    a1[2] = fmaf(wv.y, ov.z, a1[2]); a1[3] = fmaf(wv.y, ov.w, a1[3]);
  }

  // residual + write (8-lane groups cover 128B contiguous per cout row)
#pragma unroll
  for (int i = 0; i < 2; i++) {
    float* ai = (i == 0) ? a0 : a1;
    const size_t base = ((size_t)(b * 64 + co + i)) * NN + n0 + ng;
    const float4 xr = *(const float4*)&x[base];
    float4 r;
    r.x = ai[0] + xr.x; r.y = ai[1] + xr.y;
    r.z = ai[2] + xr.z; r.w = ai[3] + xr.w;
    *(float4*)&out[base] = r;
  }
}

extern "C" void kernel_launch(void* const* d_in, const int* in_sizes, int n_in,
                              void* d_out, int out_size, void* d_ws, size_t ws_size,
                              hipStream_t stream) {
  const float* x     = (const float*)d_in[0];
  const float* wqkv  = (const float*)d_in[1];
  const float* bqkv  = (const float*)d_in[2];
  const float* wproj = (const float*)d_in[3];
  const float* bproj = (const float*)d_in[4];
  float* out = (float*)d_out;

  // Workspace: Q[0,2M) K[2,4M) V[4,6M) Opart[6,22M) l[23M,23.5M)
  char* ws = (char*)d_ws;
  __bf16* Q     = (__bf16*)(ws);
  __bf16* K     = (__bf16*)(ws + (2u << 20));
  __bf16* V     = (__bf16*)(ws + (4u << 20));
  __bf16* Opart = (__bf16*)(ws + (6u << 20));   // [S,B,C,N] = 16 MiB
  float*  lpart = (float*)(ws + (23u << 20));   // SPLIT*B*N*4 = 512 KiB

  qkv_kernel<<<dim3(8, NB, 24), 256, 0, stream>>>(x, wqkv, bqkv, Q, K, V);
  flash_kernel<<<dim3(32, NB, SPLIT), 256, 0, stream>>>(Q, K, V, Opart, lpart);
  combine_proj_kernel<<<dim3(128, NB), 256, 0, stream>>>(Opart, lpart, wproj,
                                                         bproj, x, out);
}